// Round 3
// baseline (72143.170 us; speedup 1.0000x reference)
//
#include <hip/hip_runtime.h>

typedef _Float16 f16;
typedef _Float16 f16x8 __attribute__((ext_vector_type(8)));
typedef float f32x4 __attribute__((ext_vector_type(4)));

#define T_STEPS 1024
#define BATCH 128
#define DIN 512
#define HID 1024
#define OUTD 128

// ---- workspace layout (bytes) ----
#define OFF_WP1 0L          // packed [Wih1|Whh1]: 256 nb x 48 kq x 512 f16 = 12582912 B
#define OFF_WP2 12582912L   // packed [Wih2|Whh2]: 256 nb x 64 kq x 512 f16 = 16777216 B
#define OFF_WPO 29360128L   // packed Wout: 8 nb x 32 kq x 512 f16 = 262144 B
#define OFF_B1  29622272L   // bias1 (permuted) f32 : 16384 B
#define OFF_B2  29638656L   // bias2 f32 : 16384 B
#define OFF_H1H 29655040L   // h1 f16 (FRAG ORDER), 2 slots x 131072 : 524288 B
#define OFF_H2H 30179328L   // h2 f16 (FRAG ORDER), 2 slots x 131072 : 524288 B
#define OFF_BAR 30703616L   // barrier: 64 slots x 32 ints + gen @ [2048]; 4096 ints
#define OFF_ZP  30720000L   // y partials: [par2][half2][cb8][128][16] f32 = 262144 B

// h fragment layout (per slot): [m 0..7][q 0..31][lane 0..63][e 0..7] f16
// element (b, k):  m=b>>4, q=k>>5, lane=((k&31)>>3)*16 + (b&15), e=k&7
// => exactly the bytes an MFMA A-fragment load wants, contiguous 1KB per (m,q).

// packed col permutation: packed col p -> orig col = gate*1024 + unit
__device__ __host__ inline int col_perm(int p) {
    int q = p >> 5, r = p & 31;
    return (r >> 3) * 1024 + q * 8 + (r & 7);
}

// ------------------- prep kernel (unchanged) -------------------
__global__ void pack_kernel(const float* __restrict__ Wih1, const float* __restrict__ Whh1,
                            const float* __restrict__ Wih2, const float* __restrict__ Whh2,
                            const float* __restrict__ Wout,
                            const float* __restrict__ bih1, const float* __restrict__ bhh1,
                            const float* __restrict__ bih2, const float* __restrict__ bhh2,
                            f16* Wp1, f16* Wp2, f16* Wpo, float* bias1, float* bias2,
                            f16* h1h, f16* h2h, int* bar)
{
    long idx = (long)blockIdx.x * 256 + threadIdx.x;
    const long NW1 = 786432, NW2 = 1048576, NWO = 16384;
    if (idx < NW1) {
        long blk = idx >> 6; int lane = idx & 63;
        int nb = (int)(blk / 48), kb = (int)(blk % 48);
        int p = nb * 16 + (lane & 15);
        int k = kb * 32 + (lane >> 4) * 8;
        int n = col_perm(p);
        f16x8 v;
        #pragma unroll
        for (int j = 0; j < 8; j++) {
            int kk = k + j;
            float wv = (kk < 512) ? Wih1[(size_t)n * 512 + kk] : Whh1[(size_t)n * 1024 + kk - 512];
            v[j] = (f16)wv;
        }
        *(f16x8*)(Wp1 + blk * 512 + lane * 8) = v;
        return;
    }
    idx -= NW1;
    if (idx < NW2) {
        long blk = idx >> 6; int lane = idx & 63;
        int nb = (int)(blk / 64), kb = (int)(blk % 64);
        int p = nb * 16 + (lane & 15);
        int k = kb * 32 + (lane >> 4) * 8;
        int n = col_perm(p);
        f16x8 v;
        #pragma unroll
        for (int j = 0; j < 8; j++) {
            int kk = k + j;
            float wv = (kk < 1024) ? Wih2[(size_t)n * 1024 + kk] : Whh2[(size_t)n * 1024 + kk - 1024];
            v[j] = (f16)wv;
        }
        *(f16x8*)(Wp2 + blk * 512 + lane * 8) = v;
        return;
    }
    idx -= NW2;
    if (idx < NWO) {
        long blk = idx >> 6; int lane = idx & 63;
        int nb = (int)(blk / 32), kb = (int)(blk % 32);
        int n = nb * 16 + (lane & 15);
        int k = kb * 32 + (lane >> 4) * 8;
        f16x8 v;
        #pragma unroll
        for (int j = 0; j < 8; j++) v[j] = (f16)Wout[(size_t)n * 1024 + k + j];
        *(f16x8*)(Wpo + blk * 512 + lane * 8) = v;
        return;
    }
    idx -= NWO;
    if (idx < 4096) { int n = col_perm((int)idx); bias1[idx] = bih1[n] + bhh1[n]; return; }
    idx -= 4096;
    if (idx < 4096) { int n = col_perm((int)idx); bias2[idx] = bih2[n] + bhh2[n]; return; }
    idx -= 4096;
    if (idx < 65536) {
        f16x8 z = {};
        if (idx < 32768) *(f16x8*)(h1h + idx * 8) = z;
        else             *(f16x8*)(h2h + (idx - 32768) * 8) = z;
        return;
    }
    idx -= 65536;
    if (idx < 4096) bar[idx] = 0;
}

// ------------------- grid barrier (unchanged from round 1/2) -------------------
__device__ __forceinline__ void gridbar(int* bar, int p)
{
    __syncthreads();
    const int tid = threadIdx.x;
    int* gen = bar + 2048;
    if (blockIdx.x == 0) {
        if (tid == 0)
            __hip_atomic_fetch_add(bar + 0, 1, __ATOMIC_RELAXED, __HIP_MEMORY_SCOPE_AGENT);
        if (tid < 64) {
            const int tgt = 4 * (p + 1);   // 256 WGs / 64 slots = 4 per slot
            while (__hip_atomic_load(bar + tid * 32, __ATOMIC_RELAXED, __HIP_MEMORY_SCOPE_AGENT) < tgt)
                __builtin_amdgcn_s_sleep(1);
            if (tid == 0) {
                __builtin_amdgcn_fence(__ATOMIC_ACQUIRE, "agent");
                __hip_atomic_store(gen, p + 1, __ATOMIC_RELAXED, __HIP_MEMORY_SCOPE_AGENT);
            }
        }
    } else {
        if (tid == 0) {
            __hip_atomic_fetch_add(bar + (blockIdx.x & 63) * 32, 1, __ATOMIC_RELAXED, __HIP_MEMORY_SCOPE_AGENT);
            while (__hip_atomic_load(gen, __ATOMIC_RELAXED, __HIP_MEMORY_SCOPE_AGENT) < p + 1)
                __builtin_amdgcn_s_sleep(1);
            __builtin_amdgcn_fence(__ATOMIC_ACQUIRE, "agent");
        }
    }
    __syncthreads();
}

// ------------------- fragment loaders -------------------
// h (frag-order): one contiguous 1KB load per (m,q)
__device__ __forceinline__ f16x8 loadFrag(const f16* base, int m, int q)
{
    const int lane = threadIdx.x & 63;
    return *(const f16x8*)(base + ((size_t)(m * 32 + q) * 64 + lane) * 8);
}
// x (f32 row-major [128][512]): scatter load + convert
__device__ __forceinline__ f16x8 loadFragX(const float* x_t, int m, int q)
{
    const int lane = threadIdx.x & 63;
    const float* p = x_t + (size_t)(m * 16 + (lane & 15)) * DIN + q * 32 + (lane >> 4) * 8;
    float4 u0 = *(const float4*)(p);
    float4 u1 = *(const float4*)(p + 4);
    f16x8 a;
    a[0]=(f16)u0.x; a[1]=(f16)u0.y; a[2]=(f16)u0.z; a[3]=(f16)u0.w;
    a[4]=(f16)u1.x; a[5]=(f16)u1.y; a[6]=(f16)u1.z; a[7]=(f16)u1.w;
    return a;
}

// ------------------- partial-z reduction: ds_add into strided LDS -------------------
// zl stride 36 f32: row-groups {r,r+4,r+8,r+12} map to bank offsets {0,16,0,16} -> 2-way (free)
__device__ __forceinline__ void dsadd_main(float* zl, int m, f32x4 acc[2])
{
    const int lane = threadIdx.x & 63;
    const int r0 = m * 16 + ((lane >> 4) << 2);
    const int c = lane & 15;
    #pragma unroll
    for (int nt = 0; nt < 2; nt++)
        #pragma unroll
        for (int r = 0; r < 4; r++)
            atomicAdd(&zl[(r0 + r) * 36 + nt * 16 + c], acc[nt][r]);
}
// zly stride 20 f32: 2-way max
__device__ __forceinline__ void dsadd_y(float* zly, int m, f32x4 acc)
{
    const int lane = threadIdx.x & 63;
    const int r0 = m * 16 + ((lane >> 4) << 2);
    const int c = lane & 15;
    #pragma unroll
    for (int r = 0; r < 4; r++)
        atomicAdd(&zly[(r0 + r) * 20 + c], acc[r]);
}

// ------------------- per-m-tile MFMA bundles (all operands in registers) -------------------
__device__ __forceinline__ void compute_l1(const f16x8 ax[2], const f16x8 ah[4],
                                           const f16x8 Wx[2][2], const f16x8 Wh[4][2], f32x4 acc[2])
{
    #pragma unroll
    for (int s = 0; s < 2; s++) {
        acc[0] = __builtin_amdgcn_mfma_f32_16x16x32_f16(ax[s], Wx[s][0], acc[0], 0, 0, 0);
        acc[1] = __builtin_amdgcn_mfma_f32_16x16x32_f16(ax[s], Wx[s][1], acc[1], 0, 0, 0);
    }
    #pragma unroll
    for (int i = 0; i < 4; i++) {
        acc[0] = __builtin_amdgcn_mfma_f32_16x16x32_f16(ah[i], Wh[i][0], acc[0], 0, 0, 0);
        acc[1] = __builtin_amdgcn_mfma_f32_16x16x32_f16(ah[i], Wh[i][1], acc[1], 0, 0, 0);
    }
}
__device__ __forceinline__ void compute_l2(const f16x8 a1[4], const f16x8 a2[4],
                                           const f16x8 W1[4][2], const f16x8 W2[4][2], f32x4 acc[2])
{
    #pragma unroll
    for (int i = 0; i < 4; i++) {
        acc[0] = __builtin_amdgcn_mfma_f32_16x16x32_f16(a1[i], W1[i][0], acc[0], 0, 0, 0);
        acc[1] = __builtin_amdgcn_mfma_f32_16x16x32_f16(a1[i], W1[i][1], acc[1], 0, 0, 0);
    }
    #pragma unroll
    for (int i = 0; i < 4; i++) {
        acc[0] = __builtin_amdgcn_mfma_f32_16x16x32_f16(a2[i], W2[i][0], acc[0], 0, 0, 0);
        acc[1] = __builtin_amdgcn_mfma_f32_16x16x32_f16(a2[i], W2[i][1], acc[1], 0, 0, 0);
    }
}

// ------------------- gemms: m-tile loop, 1-deep register double buffer -------------------
__device__ __forceinline__ void gemm_l1(const float* x_t, const f16* h1prev, int wv,
                                        const f16x8 Wx[2][2], const f16x8 Wh[4][2], float* zl)
{
    const int qx0 = wv * 2, qh0 = wv * 4;
    f16x8 axA[2], ahA[4], axB[2], ahB[4];
    #pragma unroll
    for (int s = 0; s < 2; s++) axA[s] = loadFragX(x_t, 0, qx0 + s);
    #pragma unroll
    for (int i = 0; i < 4; i++) ahA[i] = loadFrag(h1prev, 0, qh0 + i);
    #pragma unroll
    for (int mm = 0; mm < 8; mm += 2) {
        #pragma unroll
        for (int s = 0; s < 2; s++) axB[s] = loadFragX(x_t, mm + 1, qx0 + s);
        #pragma unroll
        for (int i = 0; i < 4; i++) ahB[i] = loadFrag(h1prev, mm + 1, qh0 + i);
        f32x4 accA[2] = {};
        compute_l1(axA, ahA, Wx, Wh, accA);
        dsadd_main(zl, mm, accA);
        if (mm + 2 < 8) {
            #pragma unroll
            for (int s = 0; s < 2; s++) axA[s] = loadFragX(x_t, mm + 2, qx0 + s);
            #pragma unroll
            for (int i = 0; i < 4; i++) ahA[i] = loadFrag(h1prev, mm + 2, qh0 + i);
        }
        f32x4 accB[2] = {};
        compute_l1(axB, ahB, Wx, Wh, accB);
        dsadd_main(zl, mm + 1, accB);
    }
}

__device__ __forceinline__ void gemm_l2(const f16* h1cur, const f16* h2prev, int wv,
                                        const f16x8 W1[4][2], const f16x8 W2[4][2], float* zl)
{
    const int q0 = wv * 4;
    f16x8 a1A[4], a2A[4], a1B[4], a2B[4];
    #pragma unroll
    for (int i = 0; i < 4; i++) { a1A[i] = loadFrag(h1cur, 0, q0 + i); a2A[i] = loadFrag(h2prev, 0, q0 + i); }
    #pragma unroll
    for (int mm = 0; mm < 8; mm += 2) {
        #pragma unroll
        for (int i = 0; i < 4; i++) { a1B[i] = loadFrag(h1cur, mm + 1, q0 + i); a2B[i] = loadFrag(h2prev, mm + 1, q0 + i); }
        f32x4 accA[2] = {};
        compute_l2(a1A, a2A, W1, W2, accA);
        dsadd_main(zl, mm, accA);
        if (mm + 2 < 8) {
            #pragma unroll
            for (int i = 0; i < 4; i++) { a1A[i] = loadFrag(h1cur, mm + 2, q0 + i); a2A[i] = loadFrag(h2prev, mm + 2, q0 + i); }
        }
        f32x4 accB[2] = {};
        compute_l2(a1B, a2B, W1, W2, accB);
        dsadd_main(zl, mm + 1, accB);
    }
}

__device__ __forceinline__ void gemm_y(const f16* h2y, int w, int wv, const f16x8 Wy[2], float* zly)
{
    const int qy0 = (w >> 3) * 16 + wv * 2;
    f16x8 aA[2], aB[2];
    #pragma unroll
    for (int s = 0; s < 2; s++) aA[s] = loadFrag(h2y, 0, qy0 + s);
    #pragma unroll
    for (int mm = 0; mm < 8; mm += 2) {
        #pragma unroll
        for (int s = 0; s < 2; s++) aB[s] = loadFrag(h2y, mm + 1, qy0 + s);
        f32x4 accA = {};
        #pragma unroll
        for (int s = 0; s < 2; s++) accA = __builtin_amdgcn_mfma_f32_16x16x32_f16(aA[s], Wy[s], accA, 0, 0, 0);
        dsadd_y(zly, mm, accA);
        if (mm + 2 < 8) {
            #pragma unroll
            for (int s = 0; s < 2; s++) aA[s] = loadFrag(h2y, mm + 2, qy0 + s);
        }
        f32x4 accB = {};
        #pragma unroll
        for (int s = 0; s < 2; s++) accB = __builtin_amdgcn_mfma_f32_16x16x32_f16(aB[s], Wy[s], accB, 0, 0, 0);
        dsadd_y(zly, mm + 1, accB);
    }
}

__device__ __forceinline__ float sigm(float v) { return 1.f / (1.f + __expf(-v)); }
__device__ __forceinline__ float tanh_f(float v) { return 1.f - 2.f / (__expf(2.f * v) + 1.f); }

// ew: bias pre-baked into zl init; h written store-through in FRAG ORDER
__device__ __forceinline__ void do_ew(const float* zl, float* cst, f16* hdst, int wloc)
{
    const int j = threadIdx.x & 7;
    const int bb = threadIdx.x >> 3;
    const int qw = wloc >> 2, w3 = wloc & 3;
    #pragma unroll
    for (int i = 0; i < 2; i++) {
        const int b = bb * 2 + i;
        float zi = zl[b * 36 + j];
        float zf = zl[b * 36 + 8 + j];
        float zg = zl[b * 36 + 16 + j];
        float zo = zl[b * 36 + 24 + j];
        float c  = cst[b * 9 + j];
        float cn = sigm(zf) * c + sigm(zi) * tanh_f(zg);
        float h  = sigm(zo) * tanh_f(cn);
        cst[b * 9 + j] = cn;
        f16 hv = (f16)h;
        unsigned short us = __builtin_bit_cast(unsigned short, hv);
        // frag addr: ((b>>4)*32 + qw)*512 + (w3*16 + (b&15))*8 + j
        size_t off = (size_t)(b >> 4) * 16384 + (size_t)qw * 512 + (size_t)(w3 * 16 + (b & 15)) * 8 + j;
        __hip_atomic_store((unsigned short*)(hdst + off), us,
                           __ATOMIC_RELAXED, __HIP_MEMORY_SCOPE_AGENT);
    }
}

// ------------------- persistent pipelined LSTM kernel (512 threads = 8 waves) -------------------
__global__ void __launch_bounds__(512, 1) lstm_persist(
    const float* __restrict__ x, const float* __restrict__ b_out,
    const f16* __restrict__ Wp1, const f16* __restrict__ Wp2, const f16* __restrict__ Wpo,
    const float* __restrict__ bias1, const float* __restrict__ bias2,
    f16* h1h, f16* h2h, int* bar, float* zpart, float* __restrict__ out)
{
    __shared__ float zl[128 * 36];    // 18432 B  main-gemm reduction (bias-initialized)
    __shared__ float zly[128 * 20];   // 10240 B  y-gemm reduction
    __shared__ float cst[128 * 9];    // 4608 B   persistent c-state

    const int w = blockIdx.x;
    const bool isL1 = (w < 128);
    const int wl = isL1 ? w : (w - 128);
    const int tid = threadIdx.x;
    const int lane = tid & 63, wv = tid >> 6;

    // ---- static weights -> registers (once, before the time loop) ----
    f16x8 Wx[2][2], Wh[4][2], W1r[4][2], W2r[4][2], Wy[2];
    if (isL1) {
        const f16* B0g = Wp1 + (size_t)w * 49152;
        const f16* B1g = B0g + 48 * 512;
        #pragma unroll
        for (int s = 0; s < 2; s++) {
            Wx[s][0] = *(const f16x8*)(B0g + (size_t)(wv * 2 + s) * 512 + lane * 8);
            Wx[s][1] = *(const f16x8*)(B1g + (size_t)(wv * 2 + s) * 512 + lane * 8);
        }
        #pragma unroll
        for (int i = 0; i < 4; i++) {
            Wh[i][0] = *(const f16x8*)(B0g + (size_t)(16 + wv * 4 + i) * 512 + lane * 8);
            Wh[i][1] = *(const f16x8*)(B1g + (size_t)(16 + wv * 4 + i) * 512 + lane * 8);
        }
        if (w < 16) {
            #pragma unroll
            for (int s = 0; s < 2; s++)
                Wy[s] = *(const f16x8*)(Wpo + (size_t)((w & 7) * 32 + (w >> 3) * 16 + wv * 2 + s) * 512 + lane * 8);
        }
    } else {
        const f16* B0g = Wp2 + (size_t)wl * 65536;
        const f16* B1g = B0g + 64 * 512;
        #pragma unroll
        for (int i = 0; i < 4; i++) {
            W1r[i][0] = *(const f16x8*)(B0g + (size_t)(wv * 4 + i) * 512 + lane * 8);
            W1r[i][1] = *(const f16x8*)(B1g + (size_t)(wv * 4 + i) * 512 + lane * 8);
            W2r[i][0] = *(const f16x8*)(B0g + (size_t)(32 + wv * 4 + i) * 512 + lane * 8);
            W2r[i][1] = *(const f16x8*)(B1g + (size_t)(32 + wv * 4 + i) * 512 + lane * 8);
        }
    }

    // ---- bias + b_out -> registers ----
    const float* biasp = (isL1 ? bias1 : bias2) + (size_t)wl * 32;
    const int initRow = tid >> 2, initC = (tid & 3) * 8;
    float4 bA = *(const float4*)(biasp + initC);
    float4 bB = *(const float4*)(biasp + initC + 4);
    float4 bo4 = {};
    {
        int b = tid >> 2, oh = (tid & 3) * 4;
        if (isL1 && w < 8) bo4 = *(const float4*)(b_out + w * 16 + oh);
        (void)b;
    }
    for (int i = tid; i < 128 * 9; i += 512) cst[i] = 0.f;
    __syncthreads();

    for (int p = 0; p < T_STEPS + 3; p++) {
        // ---- out stores (w<8): consumes zpart from phase p-1 — independent, do first ----
        if (isL1 && w < 8 && p >= 3) {
            const int to = p - 3;
            const float* zp0 = zpart + (((size_t)(to & 1) * 2 + 0) * 8 + w) * 2048;
            const float* zp1 = zpart + (((size_t)(to & 1) * 2 + 1) * 8 + w) * 2048;
            int b = tid >> 2, oh = (tid & 3) * 4;
            float* dst = out + ((size_t)to * BATCH + b) * OUTD + w * 16 + oh;
            #pragma unroll
            for (int q = 0; q < 4; q++) {
                float v = zp0[b * 16 + oh + q] + zp1[b * 16 + oh + q] + ((const float*)&bo4)[q];
                __hip_atomic_store(dst + q, v, __ATOMIC_RELAXED, __HIP_MEMORY_SCOPE_AGENT);
            }
        }

        // ---- init reduction buffers (bias baked into zl) ----
        *(float4*)&zl[initRow * 36 + initC]     = bA;
        *(float4*)&zl[initRow * 36 + initC + 4] = bB;
        if (isL1 && w < 16) {
            int r = tid >> 2, c0 = (tid & 3) * 4;
            float4 z = {};
            *(float4*)&zly[r * 20 + c0] = z;
        }
        __syncthreads();

        // ---- gemms (register weights, ds_add reduction) ----
        if (isL1) {
            if (p < T_STEPS) {
                const int t1 = p;
                const f16* h1prev = h1h + (size_t)((t1 + 1) & 1) * 131072;
                gemm_l1(x + (size_t)t1 * BATCH * DIN, h1prev, wv, Wx, Wh, zl);
            }
            if (w < 16 && p >= 2 && p < T_STEPS + 2) {
                const int ty = p - 2;
                gemm_y(h2h + (size_t)(ty & 1) * 131072, w, wv, Wy, zly);
            }
        } else {
            const int t2 = p - 1;
            if (t2 >= 0 && t2 < T_STEPS) {
                const f16* h1cur  = h1h + (size_t)(t2 & 1) * 131072;
                const f16* h2prev = h2h + (size_t)((t2 + 1) & 1) * 131072;
                gemm_l2(h1cur, h2prev, wv, W1r, W2r, zl);
            }
        }
        __syncthreads();

        // ---- epilogues ----
        if (isL1) {
            if (w < 16 && p >= 2 && p < T_STEPS + 2) {
                const int ty = p - 2;
                float* zp = zpart + (((size_t)(ty & 1) * 2 + (w >> 3)) * 8 + (w & 7)) * 2048;
                int b = tid >> 2, oh = (tid & 3) * 4;
                #pragma unroll
                for (int q = 0; q < 4; q++)
                    __hip_atomic_store(zp + b * 16 + oh + q, zly[b * 20 + oh + q],
                                       __ATOMIC_RELAXED, __HIP_MEMORY_SCOPE_AGENT);
            }
            if (p < T_STEPS)
                do_ew(zl, cst, h1h + (size_t)(p & 1) * 131072, w);
        } else {
            const int t2 = p - 1;
            if (t2 >= 0 && t2 < T_STEPS)
                do_ew(zl, cst, h2h + (size_t)(t2 & 1) * 131072, wl);
        }

        gridbar(bar, p);
    }
}

extern "C" void kernel_launch(void* const* d_in, const int* in_sizes, int n_in,
                              void* d_out, int out_size, void* d_ws, size_t ws_size,
                              hipStream_t stream)
{
    const float* x    = (const float*)d_in[0];
    const float* Wih1 = (const float*)d_in[1];
    const float* Whh1 = (const float*)d_in[2];
    const float* bih1 = (const float*)d_in[3];
    const float* bhh1 = (const float*)d_in[4];
    const float* Wih2 = (const float*)d_in[5];
    const float* Whh2 = (const float*)d_in[6];
    const float* bih2 = (const float*)d_in[7];
    const float* bhh2 = (const float*)d_in[8];
    const float* Wout = (const float*)d_in[9];
    const float* bout = (const float*)d_in[10];

    char* ws = (char*)d_ws;
    f16*   Wp1 = (f16*)(ws + OFF_WP1);
    f16*   Wp2 = (f16*)(ws + OFF_WP2);
    f16*   Wpo = (f16*)(ws + OFF_WPO);
    float* b1  = (float*)(ws + OFF_B1);
    float* b2  = (float*)(ws + OFF_B2);
    f16*   h1h = (f16*)(ws + OFF_H1H);
    f16*   h2h = (f16*)(ws + OFF_H2H);
    int*   bar = (int*)(ws + OFF_BAR);
    float* zp  = (float*)(ws + OFF_ZP);
    float* out = (float*)d_out;

    // work items: 786432+1048576+16384+4096+4096+65536+4096 = 1929216 -> 7536 blocks
    hipLaunchKernelGGL(pack_kernel, dim3(7536), dim3(256), 0, stream,
                       Wih1, Whh1, Wih2, Whh2, Wout, bih1, bhh1, bih2, bhh2,
                       Wp1, Wp2, Wpo, b1, b2, h1h, h2h, bar);

    void* args[] = { (void*)&x, (void*)&bout, (void*)&Wp1, (void*)&Wp2, (void*)&Wpo,
                     (void*)&b1, (void*)&b2, (void*)&h1h, (void*)&h2h, (void*)&bar,
                     (void*)&zp, (void*)&out };
    hipError_t e = hipLaunchCooperativeKernel((void*)lstm_persist, dim3(256), dim3(512), args, 0, stream);
    if (e != hipSuccess) {
        hipLaunchKernelGGL(lstm_persist, dim3(256), dim3(512), 0, stream,
                           x, bout, Wp1, Wp2, Wpo, b1, b2, h1h, h2h, bar, zp, out);
    }
}

// Round 5
// 20485.753 us; speedup vs baseline: 3.5216x; 3.5216x over previous
//
#include <hip/hip_runtime.h>

typedef _Float16 f16;
typedef _Float16 f16x8 __attribute__((ext_vector_type(8)));
typedef float f32x4 __attribute__((ext_vector_type(4)));

#define T_STEPS 1024
#define BATCH 128
#define DIN 512
#define HID 1024
#define OUTD 128

// ---- workspace layout (bytes) ----
#define OFF_WP1 0L          // packed [Wih1|Whh1]: 256 nb x 48 kq x 512 f16 = 12582912 B
#define OFF_WP2 12582912L   // packed [Wih2|Whh2]: 256 nb x 64 kq x 512 f16 = 16777216 B
#define OFF_WPO 29360128L   // packed Wout: 8 nb x 32 kq x 512 f16 = 262144 B
#define OFF_B1  29622272L   // bias1 (permuted) f32 : 16384 B
#define OFF_B2  29638656L   // bias2 f32 : 16384 B
#define OFF_H1H 29655040L   // h1 f16, 2 slots x 128 x 1024 : 524288 B
#define OFF_H2H 30179328L   // h2 f16, 2 slots x 128 x 1024 : 524288 B
#define OFF_BAR 30703616L   // barrier: 64 slots x 32 ints + gen @ [2048]; 4096 ints
#define OFF_ZP  30720000L   // y partials: [par2][half2][cb8][128][16] f32 = 262144 B
#define OFF_XF  30982144L   // OPTIONAL x as f16, frag order [t][m8][q16][lane64][e8]: 134217728 B
#define XF_BYTES 134217728L
#define XF_T_STRIDE 65536L  // f16 elements per timestep in xf

// packed col permutation: packed col p -> orig col = gate*1024 + unit
__device__ __host__ inline int col_perm(int p) {
    int q = p >> 5, r = p & 31;
    return (r >> 3) * 1024 + q * 8 + (r & 7);
}

// ------------------- prep kernel -------------------
__global__ void pack_kernel(const float* __restrict__ Wih1, const float* __restrict__ Whh1,
                            const float* __restrict__ Wih2, const float* __restrict__ Whh2,
                            const float* __restrict__ Wout,
                            const float* __restrict__ bih1, const float* __restrict__ bhh1,
                            const float* __restrict__ bih2, const float* __restrict__ bhh2,
                            f16* Wp1, f16* Wp2, f16* Wpo, float* bias1, float* bias2,
                            f16* h1h, f16* h2h, int* bar,
                            f16* xf, const float* __restrict__ x)
{
    long idx = (long)blockIdx.x * 256 + threadIdx.x;
    const long NW1 = 786432, NW2 = 1048576, NWO = 16384;
    if (idx < NW1) {
        long blk = idx >> 6; int lane = idx & 63;
        int nb = (int)(blk / 48), kb = (int)(blk % 48);
        int p = nb * 16 + (lane & 15);
        int k = kb * 32 + (lane >> 4) * 8;
        int n = col_perm(p);
        f16x8 v;
        #pragma unroll
        for (int j = 0; j < 8; j++) {
            int kk = k + j;
            float wv = (kk < 512) ? Wih1[(size_t)n * 512 + kk] : Whh1[(size_t)n * 1024 + kk - 512];
            v[j] = (f16)wv;
        }
        *(f16x8*)(Wp1 + blk * 512 + lane * 8) = v;
        return;
    }
    idx -= NW1;
    if (idx < NW2) {
        long blk = idx >> 6; int lane = idx & 63;
        int nb = (int)(blk / 64), kb = (int)(blk % 64);
        int p = nb * 16 + (lane & 15);
        int k = kb * 32 + (lane >> 4) * 8;
        int n = col_perm(p);
        f16x8 v;
        #pragma unroll
        for (int j = 0; j < 8; j++) {
            int kk = k + j;
            float wv = (kk < 1024) ? Wih2[(size_t)n * 1024 + kk] : Whh2[(size_t)n * 1024 + kk - 1024];
            v[j] = (f16)wv;
        }
        *(f16x8*)(Wp2 + blk * 512 + lane * 8) = v;
        return;
    }
    idx -= NW2;
    if (idx < NWO) {
        long blk = idx >> 6; int lane = idx & 63;
        int nb = (int)(blk / 32), kb = (int)(blk % 32);
        int n = nb * 16 + (lane & 15);
        int k = kb * 32 + (lane >> 4) * 8;
        f16x8 v;
        #pragma unroll
        for (int j = 0; j < 8; j++) v[j] = (f16)Wout[(size_t)n * 1024 + k + j];
        *(f16x8*)(Wpo + blk * 512 + lane * 8) = v;
        return;
    }
    idx -= NWO;
    if (idx < 4096) { int n = col_perm((int)idx); bias1[idx] = bih1[n] + bhh1[n]; return; }
    idx -= 4096;
    if (idx < 4096) { int n = col_perm((int)idx); bias2[idx] = bih2[n] + bhh2[n]; return; }
    idx -= 4096;
    if (idx < 65536) {
        f16x8 z = {};
        if (idx < 32768) *(f16x8*)(h1h + idx * 8) = z;
        else             *(f16x8*)(h2h + (idx - 32768) * 8) = z;
        return;
    }
    idx -= 65536;
    if (idx < 4096) { bar[idx] = 0; return; }
    idx -= 4096;
    // optional x -> f16 frag-order conversion: [t][m][q][lane][e], 8.39M f16x8 groups
    if (xf && idx < 8388608) {
        long g = idx;
        int t = (int)(g >> 13);
        int g13 = (int)(g & 8191);
        int m = g13 >> 10, q = (g13 >> 6) & 15, lane = g13 & 63;
        int b = m * 16 + (lane & 15);
        int k0 = q * 32 + (lane >> 4) * 8;
        const float* src = x + ((size_t)t * BATCH + b) * DIN + k0;
        float4 u0 = *(const float4*)(src);
        float4 u1 = *(const float4*)(src + 4);
        f16x8 v;
        v[0]=(f16)u0.x; v[1]=(f16)u0.y; v[2]=(f16)u0.z; v[3]=(f16)u0.w;
        v[4]=(f16)u1.x; v[5]=(f16)u1.y; v[6]=(f16)u1.z; v[7]=(f16)u1.w;
        *(f16x8*)(xf + g * 8) = v;   // == xf + t*XF_T_STRIDE + ((m*16+q)*64+lane)*8
    }
}

// ------------------- grid barrier (R2: relaxed counters + acquire inv) -------------------
__device__ __forceinline__ void gridbar(int* bar, int p)
{
    __syncthreads();
    const int tid = threadIdx.x;
    int* gen = bar + 2048;
    if (blockIdx.x == 0) {
        if (tid == 0)
            __hip_atomic_fetch_add(bar + 0, 1, __ATOMIC_RELAXED, __HIP_MEMORY_SCOPE_AGENT);
        if (tid < 64) {
            const int tgt = 4 * (p + 1);   // 256 WGs / 64 slots = 4 per slot
            while (__hip_atomic_load(bar + tid * 32, __ATOMIC_RELAXED, __HIP_MEMORY_SCOPE_AGENT) < tgt)
                __builtin_amdgcn_s_sleep(1);
            if (tid == 0) {
                __builtin_amdgcn_fence(__ATOMIC_ACQUIRE, "agent");
                __hip_atomic_store(gen, p + 1, __ATOMIC_RELAXED, __HIP_MEMORY_SCOPE_AGENT);
            }
        }
    } else {
        if (tid == 0) {
            __hip_atomic_fetch_add(bar + (blockIdx.x & 63) * 32, 1, __ATOMIC_RELAXED, __HIP_MEMORY_SCOPE_AGENT);
            while (__hip_atomic_load(gen, __ATOMIC_RELAXED, __HIP_MEMORY_SCOPE_AGENT) < p + 1)
                __builtin_amdgcn_s_sleep(1);
            __builtin_amdgcn_fence(__ATOMIC_ACQUIRE, "agent");
        }
    }
    __syncthreads();
}

// ------------------- LDS weight copy (512 threads) -------------------
__device__ __forceinline__ void ldcopy(f16* dst, const f16* src, int nelem)
{
    for (int i = threadIdx.x * 8; i < nelem; i += 512 * 8)
        *(f16x8*)(dst + i) = *(const f16x8*)(src + i);
}

// ---- A-fragment chunk loaders: 8 waves, 1 m-tile (16 rows) per wave, 8 kq per chunk ----
__device__ __forceinline__ void loadA_f16(f16x8 buf[8], const f16* src, int strideE, int kOff)
{
    const int lane = threadIdx.x & 63, wave = threadIdx.x >> 6;
    const int r0 = wave * 16 + (lane & 15);
    const f16* p0 = src + (size_t)r0 * strideE + kOff + (lane >> 4) * 8;
    #pragma unroll
    for (int kb = 0; kb < 8; kb++)
        buf[kb] = *(const f16x8*)(p0 + kb * 32);
}

__device__ __forceinline__ void loadA_f32(f16x8 buf[8], const float* src, int strideE, int kOff)
{
    const int lane = threadIdx.x & 63, wave = threadIdx.x >> 6;
    const int r0 = wave * 16 + (lane & 15);
    const float* p0 = src + (size_t)r0 * strideE + kOff + (lane >> 4) * 8;
    #pragma unroll
    for (int kb = 0; kb < 8; kb++) {
        float4 u0 = *(const float4*)(p0 + kb * 32);
        float4 u1 = *(const float4*)(p0 + kb * 32 + 4);
        f16x8 a;
        a[0]=(f16)u0.x; a[1]=(f16)u0.y; a[2]=(f16)u0.z; a[3]=(f16)u0.w;
        a[4]=(f16)u1.x; a[5]=(f16)u1.y; a[6]=(f16)u1.z; a[7]=(f16)u1.w;
        buf[kb] = a;
    }
}

// ------------------- compute one 8-kq chunk from register A-buffer + LDS B -------------------
template<bool TWON>
__device__ __forceinline__ void computeChunk(const f16* B0, const f16* B1, int kqBase,
                                             f16x8 buf[8], f32x4 acc[2])
{
    const int lane = threadIdx.x & 63;
    #pragma unroll
    for (int kb = 0; kb < 8; kb++) {
        const int kq = kqBase + kb;
        f16x8 b0 = *(const f16x8*)(B0 + (size_t)kq * 512 + lane * 8);
        acc[0] = __builtin_amdgcn_mfma_f32_16x16x32_f16(buf[kb], b0, acc[0], 0, 0, 0);
        if (TWON) {
            f16x8 b1 = *(const f16x8*)(B1 + (size_t)kq * 512 + lane * 8);
            acc[1] = __builtin_amdgcn_mfma_f32_16x16x32_f16(buf[kb], b1, acc[1], 0, 0, 0);
        }
    }
}

// ------------------- generic region gemm (kept for the small y-gemm) -------------------
template<bool TWON, bool F32>
__device__ __forceinline__ void gemm_region(const void* src, int strideE, int kOff0, int kqBase, int nch,
                                            const f16* B0, const f16* B1, f32x4 acc[2])
{
    f16x8 bufA[8], bufB[8];
    if (F32) loadA_f32(bufA, (const float*)src, strideE, kOff0);
    else     loadA_f16(bufA, (const f16*)src, strideE, kOff0);
    for (int c = 0; c < nch; c += 2) {
        if (F32) loadA_f32(bufB, (const float*)src, strideE, kOff0 + (c + 1) * 256);
        else     loadA_f16(bufB, (const f16*)src, strideE, kOff0 + (c + 1) * 256);
        computeChunk<TWON>(B0, B1, kqBase + c * 8, bufA, acc);
        if (c + 2 < nch) {
            if (F32) loadA_f32(bufA, (const float*)src, strideE, kOff0 + (c + 2) * 256);
            else     loadA_f16(bufA, (const f16*)src, strideE, kOff0 + (c + 2) * 256);
        }
        computeChunk<TWON>(B0, B1, kqBase + (c + 1) * 8, bufB, acc);
    }
}

// ------------------- fused L1 pipeline: chunks 0-1 = x, 2-5 = h1prev (no boundary drain) ----
template<bool XF16>
__device__ __forceinline__ void loadChunkL1(f16x8 buf[8], const float* x_t, const f16* xf_t,
                                            const f16* h1prev, int c)
{
    const int lane = threadIdx.x & 63, wave = threadIdx.x >> 6;
    if (c < 2) {
        if (XF16) {
            // frag order: one contiguous 1KB per (wave, q); q = c*8 + kb
            const f16* p = xf_t + ((size_t)(wave * 16 + c * 8) << 9) + lane * 8;
            #pragma unroll
            for (int kb = 0; kb < 8; kb++)
                buf[kb] = *(const f16x8*)(p + ((size_t)kb << 9));
        } else {
            loadA_f32(buf, x_t, DIN, c * 256);
        }
    } else {
        loadA_f16(buf, h1prev, HID, (c - 2) * 256);
    }
}

template<bool XF16>
__device__ __forceinline__ void gemm_l1(const float* x_t, const f16* xf_t, const f16* h1prev,
                                        const f16* B0, const f16* B1, f32x4 acc[2])
{
    f16x8 bufA[8], bufB[8];
    loadChunkL1<XF16>(bufA, x_t, xf_t, h1prev, 0);
    loadChunkL1<XF16>(bufB, x_t, xf_t, h1prev, 1);
    #pragma unroll
    for (int c = 0; c < 6; c += 2) {
        computeChunk<true>(B0, B1, c * 8, bufA, acc);
        if (c + 2 < 6) loadChunkL1<XF16>(bufA, x_t, xf_t, h1prev, c + 2);
        computeChunk<true>(B0, B1, (c + 1) * 8, bufB, acc);
        if (c + 3 < 6) loadChunkL1<XF16>(bufB, x_t, xf_t, h1prev, c + 3);
    }
}

// ------------------- fused L2 pipeline: chunks 0-3 = h1cur, 4-7 = h2prev -------------------
__device__ __forceinline__ void loadChunkL2(f16x8 buf[8], const f16* h1cur, const f16* h2prev, int c)
{
    const f16* src = (c < 4) ? h1cur : h2prev;
    loadA_f16(buf, src, HID, (c & 3) * 256);
}

__device__ __forceinline__ void gemm_l2(const f16* h1cur, const f16* h2prev,
                                        const f16* B0, const f16* B1, f32x4 acc[2])
{
    f16x8 bufA[8], bufB[8];
    loadChunkL2(bufA, h1cur, h2prev, 0);
    loadChunkL2(bufB, h1cur, h2prev, 1);
    #pragma unroll
    for (int c = 0; c < 8; c += 2) {
        computeChunk<true>(B0, B1, c * 8, bufA, acc);
        if (c + 2 < 8) loadChunkL2(bufA, h1cur, h2prev, c + 2);
        computeChunk<true>(B0, B1, (c + 1) * 8, bufB, acc);
        if (c + 3 < 8) loadChunkL2(bufB, h1cur, h2prev, c + 3);
    }
}

template<bool TWON>
__device__ __forceinline__ void acc_to_zl(float* zl, f32x4 acc[2])
{
    const int lane = threadIdx.x & 63, wave = threadIdx.x >> 6;
    #pragma unroll
    for (int nt = 0; nt < (TWON ? 2 : 1); nt++)
        #pragma unroll
        for (int r = 0; r < 4; r++) {
            int row = wave * 16 + (lane >> 4) * 4 + r;
            int col = nt * 16 + (lane & 15);
            zl[row * 33 + col] = acc[nt][r];
        }
}

__device__ __forceinline__ float sigm(float v) { return 1.f / (1.f + __expf(-v)); }
__device__ __forceinline__ float tanh_f(float v) { return 1.f - 2.f / (__expf(2.f * v) + 1.f); }

// h-state store: agent-scope write-through so no L2 writeback fence is needed.
__device__ __forceinline__ void do_ew(const float* zl, float* cst, const float* biasp, int p0,
                                      f16* hdst, int u0)
{
    const int j = threadIdx.x & 7;
    const int bb = threadIdx.x >> 3;   // 0..63
    #pragma unroll
    for (int i = 0; i < 2; i++) {
        const int b = bb * 2 + i;
        float zi = zl[b * 33 + j]      + biasp[p0 + j];
        float zf = zl[b * 33 + 8 + j]  + biasp[p0 + 8 + j];
        float zg = zl[b * 33 + 16 + j] + biasp[p0 + 16 + j];
        float zo = zl[b * 33 + 24 + j] + biasp[p0 + 24 + j];
        float c  = cst[b * 9 + j];
        float cn = sigm(zf) * c + sigm(zi) * tanh_f(zg);
        float h  = sigm(zo) * tanh_f(cn);
        cst[b * 9 + j] = cn;
        f16 hv = (f16)h;
        unsigned short us = __builtin_bit_cast(unsigned short, hv);
        __hip_atomic_store((unsigned short*)(hdst + (size_t)b * HID + u0 + j), us,
                           __ATOMIC_RELAXED, __HIP_MEMORY_SCOPE_AGENT);
    }
}

// ------------------- persistent pipelined LSTM kernel (512 threads = 8 waves) -------------------
template<bool XF16>
__global__ void __launch_bounds__(512, 1) lstm_persist(
    const float* __restrict__ x, const f16* __restrict__ xf, const float* __restrict__ b_out,
    const f16* __restrict__ Wp1, const f16* __restrict__ Wp2, const f16* __restrict__ Wpo,
    const float* __restrict__ bias1, const float* __restrict__ bias2,
    f16* h1h, f16* h2h, int* bar, float* zpart, float* __restrict__ out)
{
    __shared__ f16 Wlds[65536];        // 128 KB: L1 WG: 96 KB W1 + (w<16) 16 KB Wout-slice; L2 WG: 128 KB W2
    __shared__ float zl[128 * 33];     // 16896 B
    __shared__ float cst[128 * 9];     // 4608 B persistent c-state

    const int w = blockIdx.x;
    const bool isL1 = (w < 128);
    const int wl = isL1 ? w : (w - 128);
    const int tid = threadIdx.x;

    if (isL1) {
        ldcopy(Wlds, Wp1 + (size_t)w * 49152, 49152);
        if (w < 16)
            ldcopy(Wlds + 49152, Wpo + ((size_t)(w & 7) * 32 + (w >> 3) * 16) * 512, 8192);
    } else {
        ldcopy(Wlds, Wp2 + (size_t)wl * 65536, 65536);
    }
    for (int i = tid; i < 128 * 9; i += 512) cst[i] = 0.f;

    const int ob = tid >> 2, ooh = (tid & 3) * 4;
    float4 bo4 = {};
    if (isL1 && w < 8) bo4 = *(const float4*)(b_out + w * 16 + ooh);
    __syncthreads();

    const f16* B0 = Wlds;
    const f16* B1 = isL1 ? (Wlds + 48 * 512) : (Wlds + 64 * 512);
    const f16* Bo = Wlds + 49152;

    for (int p = 0; p < T_STEPS + 3; p++) {
        // ---- out-stage zpart loads hoisted to the top: latency hides under the gemms ----
        const bool doOut = (isL1 && w < 8 && p >= 3);
        float4 za = {}, zb = {};
        if (doOut) {
            const int to = p - 3;
            const float* zp0 = zpart + (((size_t)(to & 1) * 2 + 0) * 8 + w) * 2048;
            const float* zp1 = zpart + (((size_t)(to & 1) * 2 + 1) * 8 + w) * 2048;
            za = *(const float4*)(zp0 + ob * 16 + ooh);
            zb = *(const float4*)(zp1 + ob * 16 + ooh);
        }

        if (isL1) {
            if (p < T_STEPS) {
                const int t1 = p;
                const f16* h1prev = h1h + (size_t)((t1 + 1) & 1) * (BATCH * HID);
                f32x4 acc[2] = {};
                gemm_l1<XF16>(x + (size_t)t1 * BATCH * DIN, xf + (size_t)t1 * XF_T_STRIDE,
                              h1prev, B0, B1, acc);
                __syncthreads();
                acc_to_zl<true>(zl, acc);
                __syncthreads();
                do_ew(zl, cst, bias1, w * 32, h1h + (size_t)(t1 & 1) * (BATCH * HID), w * 8);
            }
            if (w < 16 && p >= 2 && p < T_STEPS + 2) {
                const int ty = p - 2;
                const f16* h2y = h2h + (size_t)(ty & 1) * (BATCH * HID);
                f32x4 acc2[2] = {};
                gemm_region<false, false>(h2y, HID, (w >> 3) * 512, 0, 2, Bo, Bo, acc2);
                __syncthreads();
                acc_to_zl<false>(zl, acc2);
                __syncthreads();
                float* zp = zpart + (((size_t)(ty & 1) * 2 + (w >> 3)) * 8 + (w & 7)) * 2048;
                #pragma unroll
                for (int q = 0; q < 4; q++)
                    __hip_atomic_store(zp + ob * 16 + ooh + q, zl[ob * 33 + ooh + q],
                                       __ATOMIC_RELAXED, __HIP_MEMORY_SCOPE_AGENT);
            }
            if (doOut) {
                const int to = p - 3;
                float* dst = out + ((size_t)to * BATCH + ob) * OUTD + w * 16 + ooh;
                #pragma unroll
                for (int q = 0; q < 4; q++) {
                    float v = ((const float*)&za)[q] + ((const float*)&zb)[q] + ((const float*)&bo4)[q];
                    __hip_atomic_store(dst + q, v, __ATOMIC_RELAXED, __HIP_MEMORY_SCOPE_AGENT);
                }
            }
        } else {
            const int t2 = p - 1;
            if (t2 >= 0 && t2 < T_STEPS) {
                const f16* h1cur  = h1h + (size_t)(t2 & 1) * (BATCH * HID);
                const f16* h2prev = h2h + (size_t)((t2 + 1) & 1) * (BATCH * HID);
                f32x4 acc[2] = {};
                gemm_l2(h1cur, h2prev, B0, B1, acc);
                __syncthreads();
                acc_to_zl<true>(zl, acc);
                __syncthreads();
                do_ew(zl, cst, bias2, wl * 32, h2h + (size_t)(t2 & 1) * (BATCH * HID), wl * 8);
            }
        }
        gridbar(bar, p);
    }
}

extern "C" void kernel_launch(void* const* d_in, const int* in_sizes, int n_in,
                              void* d_out, int out_size, void* d_ws, size_t ws_size,
                              hipStream_t stream)
{
    const float* x    = (const float*)d_in[0];
    const float* Wih1 = (const float*)d_in[1];
    const float* Whh1 = (const float*)d_in[2];
    const float* bih1 = (const float*)d_in[3];
    const float* bhh1 = (const float*)d_in[4];
    const float* Wih2 = (const float*)d_in[5];
    const float* Whh2 = (const float*)d_in[6];
    const float* bih2 = (const float*)d_in[7];
    const float* bhh2 = (const float*)d_in[8];
    const float* Wout = (const float*)d_in[9];
    const float* bout = (const float*)d_in[10];

    char* ws = (char*)d_ws;
    f16*   Wp1 = (f16*)(ws + OFF_WP1);
    f16*   Wp2 = (f16*)(ws + OFF_WP2);
    f16*   Wpo = (f16*)(ws + OFF_WPO);
    float* b1  = (float*)(ws + OFF_B1);
    float* b2  = (float*)(ws + OFF_B2);
    f16*   h1h = (f16*)(ws + OFF_H1H);
    f16*   h2h = (f16*)(ws + OFF_H2H);
    int*   bar = (int*)(ws + OFF_BAR);
    float* zp  = (float*)(ws + OFF_ZP);
    float* out = (float*)d_out;

    const bool xf16 = (ws_size >= (size_t)(OFF_XF + XF_BYTES));
    f16* xf = xf16 ? (f16*)(ws + OFF_XF) : (f16*)(ws + OFF_WP1); // dummy non-null when unused

    // base work items: 1929216 -> 7536 blocks; +8388608 x-convert items -> 40304 blocks
    f16* xf_pack = xf16 ? xf : nullptr;
    int packBlocks = xf16 ? 40304 : 7536;
    hipLaunchKernelGGL(pack_kernel, dim3(packBlocks), dim3(256), 0, stream,
                       Wih1, Whh1, Wih2, Whh2, Wout, bih1, bhh1, bih2, bhh2,
                       Wp1, Wp2, Wpo, b1, b2, h1h, h2h, bar, xf_pack, x);

    void* args[] = { (void*)&x, (void*)&xf, (void*)&bout, (void*)&Wp1, (void*)&Wp2, (void*)&Wpo,
                     (void*)&b1, (void*)&b2, (void*)&h1h, (void*)&h2h, (void*)&bar,
                     (void*)&zp, (void*)&out };
    if (xf16) {
        hipError_t e = hipLaunchCooperativeKernel((void*)lstm_persist<true>, dim3(256), dim3(512), args, 0, stream);
        if (e != hipSuccess) {
            hipLaunchKernelGGL(lstm_persist<true>, dim3(256), dim3(512), 0, stream,
                               x, xf, bout, Wp1, Wp2, Wpo, b1, b2, h1h, h2h, bar, zp, out);
        }
    } else {
        hipError_t e = hipLaunchCooperativeKernel((void*)lstm_persist<false>, dim3(256), dim3(512), args, 0, stream);
        if (e != hipSuccess) {
            hipLaunchKernelGGL(lstm_persist<false>, dim3(256), dim3(512), 0, stream,
                               x, xf, bout, Wp1, Wp2, Wpo, b1, b2, h1h, h2h, bar, zp, out);
        }
    }
}